// Round 1
// baseline (1767.812 us; speedup 1.0000x reference)
//
#include <hip/hip_runtime.h>

#define HH 352
#define WWID 352
#define HW 123904
#define NIMG 2
#define C128 128
#define SCALE_F 0.08838834764831845f

__device__ __forceinline__ float silu_f(float v){ return v / (1.0f + __expf(-v)); }

// ============ 1x1 conv + silu (plain GEMM): O[n,co,p] = silu(sum_ci W[co,ci]*X[n,ci,p] + B[co])
// grid (HW/64, Cout/128, N), block 256. Tile: 64 px x 128 co, BK=32. Micro: 4px x 8co/thread.
__global__ __launch_bounds__(256) void k_conv1x1(const float* __restrict__ X,
                                                const float* __restrict__ W,
                                                const float* __restrict__ B,
                                                float* __restrict__ O, int Cout){
  __shared__ float Xs[32*64];      // [k][px]
  __shared__ float Wsh[128*36];    // [co][ci] stride 36 (pad: bank-conflict-free, 16B-aligned)
  const int t = threadIdx.x;
  const int p0 = blockIdx.x * 64;
  const int co0 = blockIdx.y * 128;
  const int n = blockIdx.z;
  const int ti = t & 15, tj = t >> 4;
  float4 acc[8];
#pragma unroll
  for (int j=0;j<8;j++) acc[j] = make_float4(0.f,0.f,0.f,0.f);
  const float* Xn = X + (size_t)n * C128 * HW;
  for (int k0 = 0; k0 < 128; k0 += 32){
    __syncthreads();
#pragma unroll
    for (int i=0;i<2;i++){
      int e = t + i*256;
      int px4 = (e & 15)*4, k = e >> 4;
      float4 v = *(const float4*)(Xn + (size_t)(k0+k)*HW + p0 + px4);
      *(float4*)(Xs + k*64 + px4) = v;
    }
#pragma unroll
    for (int i=0;i<4;i++){
      int e = t + i*256;
      int ci4 = (e & 7)*4, co = e >> 3;
      float4 v = *(const float4*)(W + (size_t)(co0+co)*C128 + k0 + ci4);
      *(float4*)(Wsh + co*36 + ci4) = v;
    }
    __syncthreads();
#pragma unroll
    for (int kk=0; kk<32; kk+=4){
      float4 x0 = *(const float4*)(Xs + (kk+0)*64 + ti*4);
      float4 x1 = *(const float4*)(Xs + (kk+1)*64 + ti*4);
      float4 x2 = *(const float4*)(Xs + (kk+2)*64 + ti*4);
      float4 x3 = *(const float4*)(Xs + (kk+3)*64 + ti*4);
#pragma unroll
      for (int j=0;j<8;j++){
        float4 w4 = *(const float4*)(Wsh + (tj*8+j)*36 + kk);
        acc[j].x += x0.x*w4.x + x1.x*w4.y + x2.x*w4.z + x3.x*w4.w;
        acc[j].y += x0.y*w4.x + x1.y*w4.y + x2.y*w4.z + x3.y*w4.w;
        acc[j].z += x0.z*w4.x + x1.z*w4.y + x2.z*w4.z + x3.z*w4.w;
        acc[j].w += x0.w*w4.x + x1.w*w4.y + x2.w*w4.z + x3.w*w4.w;
      }
    }
  }
  float* On = O + ((size_t)n*Cout + co0)*HW + p0;
#pragma unroll
  for (int j=0;j<8;j++){
    int co = tj*8 + j;
    float bb = B[co0+co];
    float4 a = acc[j];
    a.x = silu_f(a.x+bb); a.y = silu_f(a.y+bb); a.z = silu_f(a.z+bb); a.w = silu_f(a.w+bb);
    *(float4*)(On + (size_t)co*HW + ti*4) = a;
  }
}

// ============ 1x1 conv + silu with fused bilinear grid-sample of X (for kv). Cout=256.
// grid (HW/64, 2, N), block 256.
__global__ __launch_bounds__(256) void k_conv1x1_samp(const float* __restrict__ X,
                                                      const float* __restrict__ samp,
                                                      const float* __restrict__ W,
                                                      const float* __restrict__ B,
                                                      float* __restrict__ O){
  __shared__ float Xs[32*64];
  __shared__ float Wsh[128*36];
  __shared__ int ibs[64];
  __shared__ float4 wls[64];
  const int t = threadIdx.x;
  const int p0 = blockIdx.x * 64;
  const int co0 = blockIdx.y * 128;
  const int n = blockIdx.z;
  const int ti = t & 15, tj = t >> 4;
  if (t < 64){
    float gx = samp[((size_t)n*HW + p0 + t)*2 + 0];
    float gy = samp[((size_t)n*HW + p0 + t)*2 + 1];
    float x0f = floorf(gx), y0f = floorf(gy);
    int x0 = (int)x0f, y0 = (int)y0f;  // CLAMP=0.12 guarantees interior (gx,gy in [154,197])
    float fx = gx - x0f, fy = gy - y0f;
    ibs[t] = y0*WWID + x0;
    wls[t] = make_float4((1.f-fx)*(1.f-fy), fx*(1.f-fy), (1.f-fx)*fy, fx*fy);
  }
  __syncthreads();
  const int mypx = t & 63;
  const int ib = ibs[mypx];
  const float4 wl = wls[mypx];
  float4 acc[8];
#pragma unroll
  for (int j=0;j<8;j++) acc[j] = make_float4(0.f,0.f,0.f,0.f);
  const float* Xn = X + (size_t)n * C128 * HW;
  for (int k0 = 0; k0 < 128; k0 += 32){
    __syncthreads();
#pragma unroll
    for (int i=0;i<8;i++){
      int k = (t >> 6) + i*4;
      const float* Xc = Xn + (size_t)(k0+k)*HW + ib;
      float v = wl.x*Xc[0] + wl.y*Xc[1] + wl.z*Xc[WWID] + wl.w*Xc[WWID+1];
      Xs[k*64 + mypx] = v;
    }
#pragma unroll
    for (int i=0;i<4;i++){
      int e = t + i*256;
      int ci4 = (e & 7)*4, co = e >> 3;
      float4 v = *(const float4*)(W + (size_t)(co0+co)*C128 + k0 + ci4);
      *(float4*)(Wsh + co*36 + ci4) = v;
    }
    __syncthreads();
#pragma unroll
    for (int kk=0; kk<32; kk+=4){
      float4 x0 = *(const float4*)(Xs + (kk+0)*64 + ti*4);
      float4 x1 = *(const float4*)(Xs + (kk+1)*64 + ti*4);
      float4 x2 = *(const float4*)(Xs + (kk+2)*64 + ti*4);
      float4 x3 = *(const float4*)(Xs + (kk+3)*64 + ti*4);
#pragma unroll
      for (int j=0;j<8;j++){
        float4 w4 = *(const float4*)(Wsh + (tj*8+j)*36 + kk);
        acc[j].x += x0.x*w4.x + x1.x*w4.y + x2.x*w4.z + x3.x*w4.w;
        acc[j].y += x0.y*w4.x + x1.y*w4.y + x2.y*w4.z + x3.y*w4.w;
        acc[j].z += x0.z*w4.x + x1.z*w4.y + x2.z*w4.z + x3.z*w4.w;
        acc[j].w += x0.w*w4.x + x1.w*w4.y + x2.w*w4.z + x3.w*w4.w;
      }
    }
  }
  float* On = O + ((size_t)n*256 + co0)*HW + p0;
#pragma unroll
  for (int j=0;j<8;j++){
    int co = tj*8 + j;
    float bb = B[co0+co];
    float4 a = acc[j];
    a.x = silu_f(a.x+bb); a.y = silu_f(a.y+bb); a.z = silu_f(a.z+bb); a.w = silu_f(a.w+bb);
    *(float4*)(On + (size_t)co*HW + ti*4) = a;
  }
}

// ============ fused offset path: dw9x9(q) -> BN affine -> pw(C->2) -> pos clamp -> sample coords
// grid (11, 22, N): tile 32w x 16h, block 256 (16x16), 2 horizontal px per thread.
__global__ __launch_bounds__(256) void k_offset(const float* __restrict__ q,
                                                const float* __restrict__ dww,
                                                const float* __restrict__ dwb,
                                                const float* __restrict__ bng,
                                                const float* __restrict__ bnb,
                                                const float* __restrict__ pw,
                                                float* __restrict__ samp){
  __shared__ float s[24*40];
  const int t = threadIdx.x;
  const int X0 = blockIdx.x*32, Y0 = blockIdx.y*16, n = blockIdx.z;
  const int tx = t & 15, ty = t >> 4;
  const int px = X0 + tx*2, py = Y0 + ty;
  float o0a=0.f,o0b=0.f,o1a=0.f,o1b=0.f;
  const float inv = 1.0f / sqrtf(1.0f + 1e-5f);
  for (int c=0;c<128;c++){
    __syncthreads();
    const float* qc = q + ((size_t)n*C128 + c)*HW;
    for (int e = t; e < 960; e += 256){
      int row = e / 40;
      int col = e - row*40;
      int gr = Y0 - 4 + row, gc = X0 - 4 + col;
      float v = 0.f;
      if (gr >= 0 && gr < HH && gc >= 0 && gc < WWID) v = qc[gr*WWID + gc];
      s[e] = v;
    }
    __syncthreads();
    float sum0 = 0.f, sum1 = 0.f;
    const float* wc = dww + c*81;
#pragma unroll
    for (int r=0;r<9;r++){
      float ld[10];
#pragma unroll
      for (int m=0;m<5;m++){
        float2 v2 = *(const float2*)(s + (ty+r)*40 + tx*2 + 2*m);
        ld[2*m] = v2.x; ld[2*m+1] = v2.y;
      }
#pragma unroll
      for (int j=0;j<9;j++){
        float wv = wc[r*9+j];
        sum0 += wv*ld[j];
        sum1 += wv*ld[j+1];
      }
    }
    float g = inv * bng[c], bet = bnb[c], db = dwb[c];
    float t0 = (sum0 + db)*g + bet;
    float t1 = (sum1 + db)*g + bet;
    float p0c = pw[c], p1c = pw[C128 + c];
    o0a += p0c*t0; o0b += p0c*t1;
    o1a += p1c*t0; o1b += p1c*t1;
  }
  // pos = clip(offset + ref, +-0.12); grid = pos[..., ::-1]; to pixel coords
  const float k2 = 2.0f/351.0f;
  float ry  = (0.5f + (float)py)*k2 - 1.0f;
  float rx0 = (0.5f + (float)px)*k2 - 1.0f;
  float rx1 = (0.5f + (float)(px+1))*k2 - 1.0f;
  float pya = fminf(fmaxf(o0a + ry,  -0.12f), 0.12f);
  float pyb = fminf(fmaxf(o0b + ry,  -0.12f), 0.12f);
  float pxa = fminf(fmaxf(o1a + rx0, -0.12f), 0.12f);
  float pxb = fminf(fmaxf(o1b + rx1, -0.12f), 0.12f);
  float4 outv = make_float4((pxa+1.f)*0.5f*351.f, (pya+1.f)*0.5f*351.f,
                            (pxb+1.f)*0.5f*351.f, (pyb+1.f)*0.5f*351.f);
  *(float4*)(samp + ((size_t)n*HW + (size_t)py*WWID + px)*2) = outv;
}

// ============ window means: grid (128, 121, 2*N), one wave per (c,p,{q|k})
__global__ __launch_bounds__(64) void k_winstat(const float* __restrict__ q,
                                                const float* __restrict__ kv,
                                                float* __restrict__ qwin,
                                                float* __restrict__ kwin){
  const int c = blockIdx.x, p = blockIdx.y;
  const int n = blockIdx.z >> 1, which = blockIdx.z & 1;
  const float* src = which ? (kv + ((size_t)n*256 + c)*HW) : (q + ((size_t)n*C128 + c)*HW);
  const int py0 = (p/11)*32, px0 = (p%11)*32;
  const int l = threadIdx.x;
  float sum = 0.f;
#pragma unroll
  for (int i=0;i<16;i++){
    int e = i*64 + l;
    sum += src[(size_t)(py0 + (e>>5))*WWID + px0 + (e&31)];
  }
  for (int off=32; off>0; off>>=1) sum += __shfl_down(sum, off);
  if (l == 0){
    float* dst = which ? kwin : qwin;
    dst[((size_t)n*121 + p)*128 + c] = sum * (1.0f/1024.0f);
  }
}

// ============ routing: logits row + top-4 indices. grid (121, N), 1 wave.
__global__ __launch_bounds__(64) void k_routing(const float* __restrict__ qwin,
                                               const float* __restrict__ kwin,
                                               int* __restrict__ topidx){
  __shared__ float lg[128];
  const int p = blockIdx.x, n = blockIdx.y, l = threadIdx.x;
  const float* qr = qwin + ((size_t)n*121 + p)*128;
  const float* kb = kwin + (size_t)n*121*128;
  float a0 = 0.f, a1 = 0.f;
  const bool has1 = (l + 64) < 121;
  for (int c=0;c<128;c++){
    float qv = qr[c];
    a0 += qv * kb[(size_t)l*128 + c];
    if (has1) a1 += qv * kb[(size_t)(l+64)*128 + c];
  }
  lg[l] = a0;
  lg[64+l] = has1 ? a1 : -3.0e38f;
  __syncthreads();
  if (l == 0){
    for (int j=0;j<4;j++){
      float best = -3.0e38f; int bi = 0;
      for (int i=0;i<121;i++){ if (lg[i] > best){ best = lg[i]; bi = i; } }
      lg[bi] = -3.0e38f;
      topidx[((size_t)n*121 + p)*4 + j] = bi;
    }
  }
}

// ============ 8x8 max-pool per window -> kvd[n][p][16][256]. grid (121, N), block 256.
__global__ __launch_bounds__(256) void k_kvdpool(const float* __restrict__ kv,
                                                 float* __restrict__ kvd){
  const int p = blockIdx.x, n = blockIdx.y, t = threadIdx.x;
  const int py0 = (p/11)*32, px0 = (p%11)*32;
  const int y = t >> 3, xg = (t & 7)*4;
  const int l = t & 63, wv = t >> 6;
  for (int cc=0; cc<256; cc++){
    const float* src = kv + ((size_t)n*256 + cc)*HW + (size_t)(py0+y)*WWID + px0 + xg;
    float4 v = *(const float4*)src;
    float m = fmaxf(fmaxf(v.x, v.y), fmaxf(v.z, v.w));
    m = fmaxf(m, __shfl_xor(m, 1));
    m = fmaxf(m, __shfl_xor(m, 8));
    m = fmaxf(m, __shfl_xor(m, 16));
    m = fmaxf(m, __shfl_xor(m, 32));
    if ((l & 1) == 0 && l < 8){
      int kx = l >> 1;
      kvd[(((size_t)(n*121 + p))*16 + wv*4 + kx)*256 + cc] = m;
    }
  }
}

// ============ windowed attention. grid (121, N, 4 heads), block 256. 2 px/lane, softmax w/o max-sub
// (logits bounded ~|4| worst-case for these inputs, exp is safe in fp32).
__global__ __launch_bounds__(256) void k_attention(const float* __restrict__ q,
                                                   const float* __restrict__ kvd,
                                                   const int* __restrict__ topidx,
                                                   float* __restrict__ out){
  __shared__ float ks[64*32];
  __shared__ float vs[64*32];
  __shared__ int tix[4];
  const int p = blockIdx.x, n = blockIdx.y, h = blockIdx.z;
  const int t = threadIdx.x;
  if (t < 4) tix[t] = topidx[((size_t)n*121 + p)*4 + t];
  __syncthreads();
#pragma unroll
  for (int i=0;i<8;i++){
    int e = t + i*256;
    int d = e & 31, k = e >> 5;
    const float* kr = kvd + (((size_t)(n*121) + tix[k>>4])*16 + (k & 15))*256;
    ks[k*32 + d] = kr[h*32 + d];
    vs[k*32 + d] = kr[128 + h*32 + d];
  }
  __syncthreads();
  const int py0 = (p/11)*32, px0 = (p%11)*32;
  const int wv = t >> 6, l = t & 63;
  const float* qh = q + ((size_t)n*C128 + h*32)*HW;
  float* oh = out + ((size_t)n*C128 + h*32)*HW;
  for (int it=0; it<2; it++){
    int pxa = it*512 + wv*128 + l;
    int pxb = pxa + 64;
    size_t offa = (size_t)(py0 + (pxa>>5))*WWID + px0 + (pxa&31);
    size_t offb = (size_t)(py0 + (pxb>>5))*WWID + px0 + (pxb&31);
    float qa[32], qb[32], oa[32], ob[32];
#pragma unroll
    for (int d=0; d<32; d++){
      qa[d] = qh[(size_t)d*HW + offa] * SCALE_F;
      qb[d] = qh[(size_t)d*HW + offb] * SCALE_F;
      oa[d] = 0.f; ob[d] = 0.f;
    }
    float suma = 0.f, sumb = 0.f;
    for (int k=0; k<64; k++){
      const float4* kk4 = (const float4*)(ks + k*32);
      float da = 0.f, db = 0.f;
#pragma unroll
      for (int d4=0; d4<8; d4++){
        float4 kk = kk4[d4];
        da += qa[d4*4+0]*kk.x + qa[d4*4+1]*kk.y + qa[d4*4+2]*kk.z + qa[d4*4+3]*kk.w;
        db += qb[d4*4+0]*kk.x + qb[d4*4+1]*kk.y + qb[d4*4+2]*kk.z + qb[d4*4+3]*kk.w;
      }
      float pa = __expf(da), pb = __expf(db);
      suma += pa; sumb += pb;
      const float4* vv4 = (const float4*)(vs + k*32);
#pragma unroll
      for (int d4=0; d4<8; d4++){
        float4 vvv = vv4[d4];
        oa[d4*4+0] += pa*vvv.x; oa[d4*4+1] += pa*vvv.y; oa[d4*4+2] += pa*vvv.z; oa[d4*4+3] += pa*vvv.w;
        ob[d4*4+0] += pb*vvv.x; ob[d4*4+1] += pb*vvv.y; ob[d4*4+2] += pb*vvv.z; ob[d4*4+3] += pb*vvv.w;
      }
    }
    float ia = 1.0f/suma, ib2 = 1.0f/sumb;
#pragma unroll
    for (int d=0; d<32; d++){
      oh[(size_t)d*HW + offa] = oa[d]*ia;
      oh[(size_t)d*HW + offb] = ob[d]*ib2;
    }
  }
}

// ============ sec: depthwise 3x3 over V-half of kv, added into out. grid (121 tiles, C, N).
__global__ __launch_bounds__(256) void k_sec_add(const float* __restrict__ kv,
                                                 const float* __restrict__ secw,
                                                 const float* __restrict__ secb,
                                                 float* __restrict__ out){
  __shared__ float s[34*34];
  const int t = threadIdx.x;
  const int bx = blockIdx.x, c = blockIdx.y, n = blockIdx.z;
  const int X0 = (bx % 11)*32, Y0 = (bx / 11)*32;
  const float* src = kv + ((size_t)n*256 + 128 + c)*HW;
  for (int e = t; e < 1156; e += 256){
    int row = e / 34;
    int col = e - row*34;
    int gr = Y0 - 1 + row, gc = X0 - 1 + col;
    s[e] = (gr >= 0 && gr < HH && gc >= 0 && gc < WWID) ? src[gr*WWID + gc] : 0.f;
  }
  __syncthreads();
  const int tx = (t & 7)*4, ty = t >> 3;
  float w[9];
#pragma unroll
  for (int i=0;i<9;i++) w[i] = secw[c*9 + i];
  float4 r = make_float4(0.f,0.f,0.f,0.f);
#pragma unroll
  for (int kr=0; kr<3; kr++){
    const float* row = s + (ty + kr)*34 + tx;
    float a0=row[0],a1=row[1],a2=row[2],a3=row[3],a4=row[4],a5=row[5];
    float w0=w[kr*3], w1=w[kr*3+1], w2=w[kr*3+2];
    r.x += w0*a0 + w1*a1 + w2*a2;
    r.y += w0*a1 + w1*a2 + w2*a3;
    r.z += w0*a2 + w1*a3 + w2*a4;
    r.w += w0*a3 + w1*a4 + w2*a5;
  }
  float bb = secb[c];
  float* op = out + ((size_t)n*C128 + c)*HW + (size_t)(Y0+ty)*WWID + X0 + tx;
  float4 cur = *(float4*)op;
  cur.x += r.x + bb; cur.y += r.y + bb; cur.z += r.z + bb; cur.w += r.w + bb;
  *(float4*)op = cur;
}

extern "C" void kernel_launch(void* const* d_in, const int* in_sizes, int n_in,
                              void* d_out, int out_size, void* d_ws, size_t ws_size,
                              hipStream_t stream) {
  const float* x        = (const float*)d_in[0];
  const float* q_w      = (const float*)d_in[1];
  const float* q_b      = (const float*)d_in[2];
  const float* kv_w     = (const float*)d_in[3];
  const float* kv_b     = (const float*)d_in[4];
  const float* off_dw_w = (const float*)d_in[5];
  const float* off_dw_b = (const float*)d_in[6];
  const float* off_bn_g = (const float*)d_in[7];
  const float* off_bn_b = (const float*)d_in[8];
  const float* off_pw_w = (const float*)d_in[9];
  const float* sec_w    = (const float*)d_in[10];
  const float* sec_b    = (const float*)d_in[11];
  float* outp = (float*)d_out;

  float* qbuf  = (float*)d_ws;                               // N*128*HW
  float* kvbuf = qbuf  + (size_t)NIMG*C128*HW;               // N*256*HW
  float* samp  = kvbuf + (size_t)NIMG*256*HW;                // N*HW*2
  float* qwin  = samp  + (size_t)NIMG*HW*2;                  // N*121*128
  float* kwin  = qwin  + (size_t)NIMG*121*128;               // N*121*128
  float* kvd   = kwin  + (size_t)NIMG*121*128;               // N*121*16*256
  int*   tidx  = (int*)(kvd + (size_t)NIMG*121*16*256);      // N*121*4

  k_conv1x1<<<dim3(HW/64, 1, NIMG), 256, 0, stream>>>(x, q_w, q_b, qbuf, 128);
  k_offset<<<dim3(11, 22, NIMG), 256, 0, stream>>>(qbuf, off_dw_w, off_dw_b, off_bn_g, off_bn_b, off_pw_w, samp);
  k_conv1x1_samp<<<dim3(HW/64, 2, NIMG), 256, 0, stream>>>(x, samp, kv_w, kv_b, kvbuf);
  k_winstat<<<dim3(128, 121, 2*NIMG), 64, 0, stream>>>(qbuf, kvbuf, qwin, kwin);
  k_routing<<<dim3(121, NIMG), 64, 0, stream>>>(qwin, kwin, tidx);
  k_kvdpool<<<dim3(121, NIMG), 256, 0, stream>>>(kvbuf, kvd);
  k_attention<<<dim3(121, NIMG, 4), 256, 0, stream>>>(qbuf, kvd, tidx, outp);
  k_sec_add<<<dim3(121, 128, NIMG), 256, 0, stream>>>(kvbuf, sec_w, sec_b, outp);
}

// Round 2
// 1158.102 us; speedup vs baseline: 1.5265x; 1.5265x over previous
//
#include <hip/hip_runtime.h>

#define HH 352
#define WWID 352
#define HW 123904
#define NIMG 2
#define C128 128
#define SCALE_F 0.08838834764831845f

typedef _Float16 f16x8 __attribute__((ext_vector_type(8)));
typedef float f32x4 __attribute__((ext_vector_type(4)));

__device__ __forceinline__ float silu_f(float v){ return v / (1.0f + __expf(-v)); }

// ============ weight pre-swizzle into A-fragment order for mfma_f32_16x16x32_f16.
// Frag (ct, kc): lane l holds W[ct*16 + (l&15)][kc*32 + (l>>4)*8 + j], j=0..7.
// Flat: Wf[((ct*4 + kc)*64 + l)*8 + j].  nct = Cout/16.
__global__ __launch_bounds__(256) void k_wprep(const float* __restrict__ W,
                                               _Float16* __restrict__ Wf, int nct){
  int e = blockIdx.x*256 + threadIdx.x;
  if (e >= nct*256) return;
  int l = e & 63, kc = (e>>6)&3, ct = e>>8;
  const float* src = W + (size_t)(ct*16 + (l&15))*128 + kc*32 + (l>>4)*8;
  f16x8 pk;
#pragma unroll
  for (int j=0;j<8;j++) pk[j] = (_Float16)src[j];
  *(f16x8*)(Wf + (size_t)e*8) = pk;
}

// ============ 1x1 conv + silu via fp16 MFMA (fp32 acc). COW = co per wave (Cout = 4*COW).
// grid (HW/64, 1, N), block 256 (4 waves). Tile: 64 px x Cout. K=128 in 4 chunks of 32.
// SAMP: X values are bilinear-sampled at coords from `samp` (interior guaranteed by CLAMP).
template<int COW, bool SAMP>
__global__ __launch_bounds__(256) void k_conv_mfma(const float* __restrict__ X,
                                                   const float* __restrict__ samp,
                                                   const _Float16* __restrict__ Wf,
                                                   const float* __restrict__ B,
                                                   float* __restrict__ O){
  constexpr int Cout = COW*4;
  constexpr int MT = COW/16;
  __shared__ _Float16 Xs[16*64*8];   // [kb][px][8k] f16 = 16 KB
  __shared__ int ibs[64];
  __shared__ float4 wls[64];
  const int t = threadIdx.x;
  const int p0 = blockIdx.x*64;
  const int n = blockIdx.z;
  const int wv = t>>6, l = t&63;
  const float* Xn = X + (size_t)n*C128*HW;
  if (SAMP){
    if (t < 64){
      float gx = samp[((size_t)n*HW + p0 + t)*2 + 0];
      float gy = samp[((size_t)n*HW + p0 + t)*2 + 1];
      float x0f = floorf(gx), y0f = floorf(gy);
      int x0 = (int)x0f, y0 = (int)y0f;  // CLAMP=0.12 -> gx,gy in [154,197]: interior
      float fx = gx - x0f, fy = gy - y0f;
      ibs[t] = y0*WWID + x0;
      wls[t] = make_float4((1.f-fx)*(1.f-fy), fx*(1.f-fy), (1.f-fx)*fy, fx*fy);
    }
    __syncthreads();
  }
  int ib = 0; float4 wl = make_float4(0.f,0.f,0.f,0.f);
  if (SAMP){ ib = ibs[l]; wl = wls[l]; }
  // stage X (f16) into B-frag-friendly layout
#pragma unroll
  for (int it=0; it<4; it++){
    int kb = it*4 + wv;
    f16x8 pk;
#pragma unroll
    for (int j=0;j<8;j++){
      int ci = kb*8 + j;
      float v;
      if (SAMP){
        const float* Xc = Xn + (size_t)ci*HW + ib;
        v = wl.x*Xc[0] + wl.y*Xc[1] + wl.z*Xc[WWID] + wl.w*Xc[WWID+1];
      } else {
        v = Xn[(size_t)ci*HW + p0 + l];
      }
      pk[j] = (_Float16)v;
    }
    *(f16x8*)(&Xs[(kb*64 + l)*8]) = pk;
  }
  __syncthreads();
  const int quad = l>>4, li = l&15;
  f32x4 acc[MT][4];
#pragma unroll
  for (int m=0;m<MT;m++)
#pragma unroll
    for (int nt=0;nt<4;nt++){ acc[m][nt][0]=0.f; acc[m][nt][1]=0.f; acc[m][nt][2]=0.f; acc[m][nt][3]=0.f; }
  const _Float16* Wfw = Wf + (size_t)(wv*MT)*4*64*8;
#pragma unroll
  for (int kc=0; kc<4; kc++){
    f16x8 b[4];
#pragma unroll
    for (int nt=0; nt<4; nt++)
      b[nt] = *(const f16x8*)(&Xs[((kc*4 + quad)*64 + nt*16 + li)*8]);
    f16x8 a[MT];
#pragma unroll
    for (int m=0;m<MT;m++)
      a[m] = *(const f16x8*)(Wfw + (size_t)((m*4 + kc)*64 + l)*8);
#pragma unroll
    for (int m=0;m<MT;m++)
#pragma unroll
      for (int nt=0;nt<4;nt++)
        acc[m][nt] = __builtin_amdgcn_mfma_f32_16x16x32_f16(a[m], b[nt], acc[m][nt], 0, 0, 0);
  }
  // epilogue: bias + silu, store. D layout: row(co)=quad*4+reg, col(px)=lane&15.
#pragma unroll
  for (int m=0;m<MT;m++){
    int cob = wv*COW + m*16 + quad*4;
#pragma unroll
    for (int r=0;r<4;r++){
      float bb = B[cob + r];
      float* Orow = O + ((size_t)n*Cout + cob + r)*HW + p0;
#pragma unroll
      for (int nt=0;nt<4;nt++){
        Orow[nt*16 + li] = silu_f(acc[m][nt][r] + bb);
      }
    }
  }
}

// ============ fused offset path: dw9x9(q) -> BN affine -> pw(C->2) -> pos clamp -> sample coords
// grid (11, 22, N): tile 32w x 16h, block 256 (16x16), 2 horizontal px per thread.
__global__ __launch_bounds__(256) void k_offset(const float* __restrict__ q,
                                                const float* __restrict__ dww,
                                                const float* __restrict__ dwb,
                                                const float* __restrict__ bng,
                                                const float* __restrict__ bnb,
                                                const float* __restrict__ pw,
                                                float* __restrict__ samp){
  __shared__ float s[24*40];
  const int t = threadIdx.x;
  const int X0 = blockIdx.x*32, Y0 = blockIdx.y*16, n = blockIdx.z;
  const int tx = t & 15, ty = t >> 4;
  const int px = X0 + tx*2, py = Y0 + ty;
  float o0a=0.f,o0b=0.f,o1a=0.f,o1b=0.f;
  const float inv = 1.0f / sqrtf(1.0f + 1e-5f);
  for (int c=0;c<128;c++){
    __syncthreads();
    const float* qc = q + ((size_t)n*C128 + c)*HW;
    for (int e = t; e < 960; e += 256){
      int row = e / 40;
      int col = e - row*40;
      int gr = Y0 - 4 + row, gc = X0 - 4 + col;
      float v = 0.f;
      if (gr >= 0 && gr < HH && gc >= 0 && gc < WWID) v = qc[gr*WWID + gc];
      s[e] = v;
    }
    __syncthreads();
    float sum0 = 0.f, sum1 = 0.f;
    const float* wc = dww + c*81;
#pragma unroll
    for (int r=0;r<9;r++){
      float ld[10];
#pragma unroll
      for (int m=0;m<5;m++){
        float2 v2 = *(const float2*)(s + (ty+r)*40 + tx*2 + 2*m);
        ld[2*m] = v2.x; ld[2*m+1] = v2.y;
      }
#pragma unroll
      for (int j=0;j<9;j++){
        float wv = wc[r*9+j];
        sum0 += wv*ld[j];
        sum1 += wv*ld[j+1];
      }
    }
    float g = inv * bng[c], bet = bnb[c], db = dwb[c];
    float t0 = (sum0 + db)*g + bet;
    float t1 = (sum1 + db)*g + bet;
    float p0c = pw[c], p1c = pw[C128 + c];
    o0a += p0c*t0; o0b += p0c*t1;
    o1a += p1c*t0; o1b += p1c*t1;
  }
  const float k2 = 2.0f/351.0f;
  float ry  = (0.5f + (float)py)*k2 - 1.0f;
  float rx0 = (0.5f + (float)px)*k2 - 1.0f;
  float rx1 = (0.5f + (float)(px+1))*k2 - 1.0f;
  float pya = fminf(fmaxf(o0a + ry,  -0.12f), 0.12f);
  float pyb = fminf(fmaxf(o0b + ry,  -0.12f), 0.12f);
  float pxa = fminf(fmaxf(o1a + rx0, -0.12f), 0.12f);
  float pxb = fminf(fmaxf(o1b + rx1, -0.12f), 0.12f);
  float4 outv = make_float4((pxa+1.f)*0.5f*351.f, (pya+1.f)*0.5f*351.f,
                            (pxb+1.f)*0.5f*351.f, (pyb+1.f)*0.5f*351.f);
  *(float4*)(samp + ((size_t)n*HW + (size_t)py*WWID + px)*2) = outv;
}

// ============ window means: grid (128, 121, 2*N), one wave per (c,p,{q|k})
__global__ __launch_bounds__(64) void k_winstat(const float* __restrict__ q,
                                                const float* __restrict__ kv,
                                                float* __restrict__ qwin,
                                                float* __restrict__ kwin){
  const int c = blockIdx.x, p = blockIdx.y;
  const int n = blockIdx.z >> 1, which = blockIdx.z & 1;
  const float* src = which ? (kv + ((size_t)n*256 + c)*HW) : (q + ((size_t)n*C128 + c)*HW);
  const int py0 = (p/11)*32, px0 = (p%11)*32;
  const int l = threadIdx.x;
  float sum = 0.f;
#pragma unroll
  for (int i=0;i<16;i++){
    int e = i*64 + l;
    sum += src[(size_t)(py0 + (e>>5))*WWID + px0 + (e&31)];
  }
  for (int off=32; off>0; off>>=1) sum += __shfl_down(sum, off);
  if (l == 0){
    float* dst = which ? kwin : qwin;
    dst[((size_t)n*121 + p)*128 + c] = sum * (1.0f/1024.0f);
  }
}

// ============ routing: logits row + top-4 indices. grid (121, N), 1 wave.
__global__ __launch_bounds__(64) void k_routing(const float* __restrict__ qwin,
                                               const float* __restrict__ kwin,
                                               int* __restrict__ topidx){
  __shared__ float lg[128];
  const int p = blockIdx.x, n = blockIdx.y, l = threadIdx.x;
  const float* qr = qwin + ((size_t)n*121 + p)*128;
  const float* kb = kwin + (size_t)n*121*128;
  float a0 = 0.f, a1 = 0.f;
  const bool has1 = (l + 64) < 121;
  for (int c=0;c<128;c++){
    float qv = qr[c];
    a0 += qv * kb[(size_t)l*128 + c];
    if (has1) a1 += qv * kb[(size_t)(l+64)*128 + c];
  }
  lg[l] = a0;
  lg[64+l] = has1 ? a1 : -3.0e38f;
  __syncthreads();
  if (l == 0){
    for (int j=0;j<4;j++){
      float best = -3.0e38f; int bi = 0;
      for (int i=0;i<121;i++){ if (lg[i] > best){ best = lg[i]; bi = i; } }
      lg[bi] = -3.0e38f;
      topidx[((size_t)n*121 + p)*4 + j] = bi;
    }
  }
}

// ============ 8x8 max-pool per window -> kvd[n][p][16][256]. grid (121, N, 8), block 256.
__global__ __launch_bounds__(256) void k_kvdpool(const float* __restrict__ kv,
                                                 float* __restrict__ kvd){
  const int p = blockIdx.x, n = blockIdx.y, t = threadIdx.x;
  const int c0 = blockIdx.z * 32;
  const int py0 = (p/11)*32, px0 = (p%11)*32;
  const int y = t >> 3, xg = (t & 7)*4;
  const int l = t & 63, wv = t >> 6;
  for (int cc=c0; cc<c0+32; cc++){
    const float* src = kv + ((size_t)n*256 + cc)*HW + (size_t)(py0+y)*WWID + px0 + xg;
    float4 v = *(const float4*)src;
    float m = fmaxf(fmaxf(v.x, v.y), fmaxf(v.z, v.w));
    m = fmaxf(m, __shfl_xor(m, 1));
    m = fmaxf(m, __shfl_xor(m, 8));
    m = fmaxf(m, __shfl_xor(m, 16));
    m = fmaxf(m, __shfl_xor(m, 32));
    if ((l & 1) == 0 && l < 8){
      int kx = l >> 1;
      kvd[(((size_t)(n*121 + p))*16 + wv*4 + kx)*256 + cc] = m;
    }
  }
}

// ============ windowed attention. grid (121, N, 4 heads), block 256. 2 px/lane.
__global__ __launch_bounds__(256) void k_attention(const float* __restrict__ q,
                                                   const float* __restrict__ kvd,
                                                   const int* __restrict__ topidx,
                                                   float* __restrict__ out){
  __shared__ float ks[64*32];
  __shared__ float vs[64*32];
  __shared__ int tix[4];
  const int p = blockIdx.x, n = blockIdx.y, h = blockIdx.z;
  const int t = threadIdx.x;
  if (t < 4) tix[t] = topidx[((size_t)n*121 + p)*4 + t];
  __syncthreads();
#pragma unroll
  for (int i=0;i<8;i++){
    int e = t + i*256;
    int d = e & 31, k = e >> 5;
    const float* kr = kvd + (((size_t)(n*121) + tix[k>>4])*16 + (k & 15))*256;
    ks[k*32 + d] = kr[h*32 + d];
    vs[k*32 + d] = kr[128 + h*32 + d];
  }
  __syncthreads();
  const int py0 = (p/11)*32, px0 = (p%11)*32;
  const int wv = t >> 6, l = t & 63;
  const float* qh = q + ((size_t)n*C128 + h*32)*HW;
  float* oh = out + ((size_t)n*C128 + h*32)*HW;
  for (int it=0; it<2; it++){
    int pxa = it*512 + wv*128 + l;
    int pxb = pxa + 64;
    size_t offa = (size_t)(py0 + (pxa>>5))*WWID + px0 + (pxa&31);
    size_t offb = (size_t)(py0 + (pxb>>5))*WWID + px0 + (pxb&31);
    float qa[32], qb[32], oa[32], ob[32];
#pragma unroll
    for (int d=0; d<32; d++){
      qa[d] = qh[(size_t)d*HW + offa] * SCALE_F;
      qb[d] = qh[(size_t)d*HW + offb] * SCALE_F;
      oa[d] = 0.f; ob[d] = 0.f;
    }
    float suma = 0.f, sumb = 0.f;
    for (int k=0; k<64; k++){
      const float4* kk4 = (const float4*)(ks + k*32);
      float da = 0.f, db = 0.f;
#pragma unroll
      for (int d4=0; d4<8; d4++){
        float4 kk = kk4[d4];
        da += qa[d4*4+0]*kk.x + qa[d4*4+1]*kk.y + qa[d4*4+2]*kk.z + qa[d4*4+3]*kk.w;
        db += qb[d4*4+0]*kk.x + qb[d4*4+1]*kk.y + qb[d4*4+2]*kk.z + qb[d4*4+3]*kk.w;
      }
      float pa = __expf(da), pb = __expf(db);
      suma += pa; sumb += pb;
      const float4* vv4 = (const float4*)(vs + k*32);
#pragma unroll
      for (int d4=0; d4<8; d4++){
        float4 vvv = vv4[d4];
        oa[d4*4+0] += pa*vvv.x; oa[d4*4+1] += pa*vvv.y; oa[d4*4+2] += pa*vvv.z; oa[d4*4+3] += pa*vvv.w;
        ob[d4*4+0] += pb*vvv.x; ob[d4*4+1] += pb*vvv.y; ob[d4*4+2] += pb*vvv.z; ob[d4*4+3] += pb*vvv.w;
      }
    }
    float ia = 1.0f/suma, ib2 = 1.0f/sumb;
#pragma unroll
    for (int d=0; d<32; d++){
      oh[(size_t)d*HW + offa] = oa[d]*ia;
      oh[(size_t)d*HW + offb] = ob[d]*ib2;
    }
  }
}

// ============ sec: depthwise 3x3 over V-half of kv, added into out. grid (121 tiles, C, N).
__global__ __launch_bounds__(256) void k_sec_add(const float* __restrict__ kv,
                                                 const float* __restrict__ secw,
                                                 const float* __restrict__ secb,
                                                 float* __restrict__ out){
  __shared__ float s[34*34];
  const int t = threadIdx.x;
  const int bx = blockIdx.x, c = blockIdx.y, n = blockIdx.z;
  const int X0 = (bx % 11)*32, Y0 = (bx / 11)*32;
  const float* src = kv + ((size_t)n*256 + 128 + c)*HW;
  for (int e = t; e < 1156; e += 256){
    int row = e / 34;
    int col = e - row*34;
    int gr = Y0 - 1 + row, gc = X0 - 1 + col;
    s[e] = (gr >= 0 && gr < HH && gc >= 0 && gc < WWID) ? src[gr*WWID + gc] : 0.f;
  }
  __syncthreads();
  const int tx = (t & 7)*4, ty = t >> 3;
  float w[9];
#pragma unroll
  for (int i=0;i<9;i++) w[i] = secw[c*9 + i];
  float4 r = make_float4(0.f,0.f,0.f,0.f);
#pragma unroll
  for (int kr=0; kr<3; kr++){
    const float* row = s + (ty + kr)*34 + tx;
    float a0=row[0],a1=row[1],a2=row[2],a3=row[3],a4=row[4],a5=row[5];
    float w0=w[kr*3], w1=w[kr*3+1], w2=w[kr*3+2];
    r.x += w0*a0 + w1*a1 + w2*a2;
    r.y += w0*a1 + w1*a2 + w2*a3;
    r.z += w0*a2 + w1*a3 + w2*a4;
    r.w += w0*a3 + w1*a4 + w2*a5;
  }
  float bb = secb[c];
  float* op = out + ((size_t)n*C128 + c)*HW + (size_t)(Y0+ty)*WWID + X0 + tx;
  float4 cur = *(float4*)op;
  cur.x += r.x + bb; cur.y += r.y + bb; cur.z += r.z + bb; cur.w += r.w + bb;
  *(float4*)op = cur;
}

extern "C" void kernel_launch(void* const* d_in, const int* in_sizes, int n_in,
                              void* d_out, int out_size, void* d_ws, size_t ws_size,
                              hipStream_t stream) {
  const float* x        = (const float*)d_in[0];
  const float* q_w      = (const float*)d_in[1];
  const float* q_b      = (const float*)d_in[2];
  const float* kv_w     = (const float*)d_in[3];
  const float* kv_b     = (const float*)d_in[4];
  const float* off_dw_w = (const float*)d_in[5];
  const float* off_dw_b = (const float*)d_in[6];
  const float* off_bn_g = (const float*)d_in[7];
  const float* off_bn_b = (const float*)d_in[8];
  const float* off_pw_w = (const float*)d_in[9];
  const float* sec_w    = (const float*)d_in[10];
  const float* sec_b    = (const float*)d_in[11];
  float* outp = (float*)d_out;

  float* qbuf  = (float*)d_ws;                               // N*128*HW
  float* kvbuf = qbuf  + (size_t)NIMG*C128*HW;               // N*256*HW
  float* samp  = kvbuf + (size_t)NIMG*256*HW;                // N*HW*2
  float* qwin  = samp  + (size_t)NIMG*HW*2;                  // N*121*128
  float* kwin  = qwin  + (size_t)NIMG*121*128;               // N*121*128
  float* kvd   = kwin  + (size_t)NIMG*121*128;               // N*121*16*256
  int*   tidx  = (int*)(kvd + (size_t)NIMG*121*16*256);      // N*121*4
  _Float16* wfq  = (_Float16*)(tidx + NIMG*121*4);           // 128/16*4*64*8 = 16384 f16
  _Float16* wfkv = wfq + 16384;                              // 256/16*4*64*8 = 32768 f16

  k_wprep<<<dim3(8), 256, 0, stream>>>(q_w, wfq, 8);
  k_wprep<<<dim3(16), 256, 0, stream>>>(kv_w, wfkv, 16);
  k_conv_mfma<32, false><<<dim3(HW/64, 1, NIMG), 256, 0, stream>>>(x, nullptr, wfq, q_b, qbuf);
  k_offset<<<dim3(11, 22, NIMG), 256, 0, stream>>>(qbuf, off_dw_w, off_dw_b, off_bn_g, off_bn_b, off_pw_w, samp);
  k_conv_mfma<64, true><<<dim3(HW/64, 1, NIMG), 256, 0, stream>>>(x, samp, wfkv, kv_b, kvbuf);
  k_winstat<<<dim3(128, 121, 2*NIMG), 64, 0, stream>>>(qbuf, kvbuf, qwin, kwin);
  k_routing<<<dim3(121, NIMG), 64, 0, stream>>>(qwin, kwin, tidx);
  k_kvdpool<<<dim3(121, NIMG, 8), 256, 0, stream>>>(kvbuf, kvd);
  k_attention<<<dim3(121, NIMG, 4), 256, 0, stream>>>(qbuf, kvd, tidx, outp);
  k_sec_add<<<dim3(121, 128, NIMG), 256, 0, stream>>>(kvbuf, sec_w, sec_b, outp);
}

// Round 3
// 984.796 us; speedup vs baseline: 1.7951x; 1.1760x over previous
//
#include <hip/hip_runtime.h>

#define HH 352
#define WWID 352
#define HW 123904
#define NIMG 2
#define C128 128
#define SCALE_F 0.08838834764831845f

typedef _Float16 f16x8 __attribute__((ext_vector_type(8)));
typedef float f32x4 __attribute__((ext_vector_type(4)));

__device__ __forceinline__ float silu_f(float v){ return v / (1.0f + __expf(-v)); }

// order-monotonic float<->uint for atomicMax on fp32 (handles negatives)
__device__ __forceinline__ unsigned enc_f(float v){
  unsigned u = __float_as_uint(v);
  return (u & 0x80000000u) ? ~u : (u | 0x80000000u);
}
__device__ __forceinline__ float dec_f(unsigned k){
  return __uint_as_float((k & 0x80000000u) ? (k & 0x7fffffffu) : ~k);
}

// ============ weight pre-swizzle into A-fragment order for mfma_f32_16x16x32_f16.
__global__ __launch_bounds__(256) void k_wprep(const float* __restrict__ W,
                                               _Float16* __restrict__ Wf, int nct){
  int e = blockIdx.x*256 + threadIdx.x;
  if (e >= nct*256) return;
  int l = e & 63, kc = (e>>6)&3, ct = e>>8;
  const float* src = W + (size_t)(ct*16 + (l&15))*128 + kc*32 + (l>>4)*8;
  f16x8 pk;
#pragma unroll
  for (int j=0;j<8;j++) pk[j] = (_Float16)src[j];
  *(f16x8*)(Wf + (size_t)e*8) = pk;
}

// ============ 1x1 conv + silu via fp16 MFMA, with fused epilogue reductions:
//  FUSEW: window sums of co<128 output -> winsum (atomicAdd, for routing; scale-free)
//  FUSEP: 8x8 window max-pool -> kvdk (uint-encoded atomicMax)
// A 16-px nt-group is 16-aligned and 352%32==0, so it never crosses a window boundary.
template<int COW, bool SAMP, bool FUSEW, bool FUSEP>
__global__ __launch_bounds__(256) void k_conv_mfma(const float* __restrict__ X,
                                                   const float* __restrict__ samp,
                                                   const _Float16* __restrict__ Wf,
                                                   const float* __restrict__ B,
                                                   float* __restrict__ O,
                                                   float* __restrict__ winsum,
                                                   unsigned* __restrict__ kvdk){
  constexpr int Cout = COW*4;
  constexpr int MT = COW/16;
  __shared__ _Float16 Xs[16*64*8];
  __shared__ int ibs[64];
  __shared__ float4 wls[64];
  const int t = threadIdx.x;
  const int p0 = blockIdx.x*64;
  const int n = blockIdx.z;
  const int wv = t>>6, l = t&63;
  const float* Xn = X + (size_t)n*C128*HW;
  if (SAMP){
    if (t < 64){
      float gx = samp[((size_t)n*HW + p0 + t)*2 + 0];
      float gy = samp[((size_t)n*HW + p0 + t)*2 + 1];
      float x0f = floorf(gx), y0f = floorf(gy);
      int x0 = (int)x0f, y0 = (int)y0f;  // CLAMP=0.12 -> interior guaranteed
      float fx = gx - x0f, fy = gy - y0f;
      ibs[t] = y0*WWID + x0;
      wls[t] = make_float4((1.f-fx)*(1.f-fy), fx*(1.f-fy), (1.f-fx)*fy, fx*fy);
    }
    __syncthreads();
  }
  int ib = 0; float4 wl = make_float4(0.f,0.f,0.f,0.f);
  if (SAMP){ ib = ibs[l]; wl = wls[l]; }
#pragma unroll
  for (int it=0; it<4; it++){
    int kb = it*4 + wv;
    f16x8 pk;
#pragma unroll
    for (int j=0;j<8;j++){
      int ci = kb*8 + j;
      float v;
      if (SAMP){
        const float* Xc = Xn + (size_t)ci*HW + ib;
        v = wl.x*Xc[0] + wl.y*Xc[1] + wl.z*Xc[WWID] + wl.w*Xc[WWID+1];
      } else {
        v = Xn[(size_t)ci*HW + p0 + l];
      }
      pk[j] = (_Float16)v;
    }
    *(f16x8*)(&Xs[(kb*64 + l)*8]) = pk;
  }
  __syncthreads();
  const int quad = l>>4, li = l&15;
  f32x4 acc[MT][4];
#pragma unroll
  for (int m=0;m<MT;m++)
#pragma unroll
    for (int nt=0;nt<4;nt++){ acc[m][nt][0]=0.f; acc[m][nt][1]=0.f; acc[m][nt][2]=0.f; acc[m][nt][3]=0.f; }
  const _Float16* Wfw = Wf + (size_t)(wv*MT)*4*64*8;
#pragma unroll
  for (int kc=0; kc<4; kc++){
    f16x8 b[4];
#pragma unroll
    for (int nt=0; nt<4; nt++)
      b[nt] = *(const f16x8*)(&Xs[((kc*4 + quad)*64 + nt*16 + li)*8]);
    f16x8 a[MT];
#pragma unroll
    for (int m=0;m<MT;m++)
      a[m] = *(const f16x8*)(Wfw + (size_t)((m*4 + kc)*64 + l)*8);
#pragma unroll
    for (int m=0;m<MT;m++)
#pragma unroll
      for (int nt=0;nt<4;nt++)
        acc[m][nt] = __builtin_amdgcn_mfma_f32_16x16x32_f16(a[m], b[nt], acc[m][nt], 0, 0, 0);
  }
  // epilogue: bias+silu, store, fused window reductions.
#pragma unroll
  for (int m=0;m<MT;m++){
    int cob = wv*COW + m*16 + quad*4;
#pragma unroll
    for (int r=0;r<4;r++){
      int co = cob + r;
      float bb = B[co];
      float* Orow = O + ((size_t)n*Cout + co)*HW + p0;
#pragma unroll
      for (int nt=0;nt<4;nt++){
        float y = silu_f(acc[m][nt][r] + bb);
        Orow[nt*16 + li] = y;
        if (FUSEW || FUSEP){
          int pl = p0 + nt*16;                  // uniform per block
          int row = pl / WWID, col = pl - (pl/WWID)*WWID;
          int p = (row>>5)*11 + (col>>5);
          if (FUSEW && co < 128){
            float ssum = y;
            ssum += __shfl_xor(ssum,1); ssum += __shfl_xor(ssum,2);
            ssum += __shfl_xor(ssum,4); ssum += __shfl_xor(ssum,8);
            if (li == 0)
              atomicAdd(winsum + ((size_t)n*121 + p)*128 + co, ssum);
          }
          if (FUSEP){
            float mx = y;
            mx = fmaxf(mx, __shfl_xor(mx,1));
            mx = fmaxf(mx, __shfl_xor(mx,2));
            mx = fmaxf(mx, __shfl_xor(mx,4));
            if ((li & 7) == 0){
              int cell = ((row&31)>>3)*4 + ((col&31)>>3) + (li>>3);
              atomicMax(kvdk + ((((size_t)n*121 + p)*16 + cell)*256 + co), enc_f(mx));
            }
          }
        }
      }
    }
  }
}

// ============ offset path, channel-split: each block does 32 channels of dw9x9+BN+pw over a
// 32x16 tile, partial-reduced into offacc via atomicAdd. grid (11, 22, N*4), block 256.
// 4 channels per LDS stage (8 stages), register prefetch of next stage over compute.
__global__ __launch_bounds__(256) void k_offset_part(const float* __restrict__ q,
                                                     const float* __restrict__ dww,
                                                     const float* __restrict__ dwb,
                                                     const float* __restrict__ bng,
                                                     const float* __restrict__ bnb,
                                                     const float* __restrict__ pw,
                                                     float* __restrict__ offacc){
  __shared__ float s[3840];   // [4ch][960], 960 = 24 rows x 40 cols halo tile
  const int t = threadIdx.x;
  const int X0 = blockIdx.x*32, Y0 = blockIdx.y*16;
  const int n = blockIdx.z >> 2, c0 = (blockIdx.z & 3)*32;
  const int tx = t & 15, ty = t >> 4;
  const int px = X0 + tx*2, py = Y0 + ty;
  const float inv = 1.0f / sqrtf(1.0f + 1e-5f);
  float o0a=0.f,o0b=0.f,o1a=0.f,o1b=0.f;
  float pf[15];
  const float* qn = q + (size_t)n*C128*HW;
  auto issue = [&](int stage){
    int cbase = c0 + stage*4;
#pragma unroll
    for (int i=0;i<15;i++){
      int e = t + i*256;
      int ch = e/960, idx = e - ch*960;
      int rr = idx/40, cc2 = idx - rr*40;
      int gr = Y0 - 4 + rr, gc = X0 - 4 + cc2;
      float v = 0.f;
      if (gr>=0 && gr<HH && gc>=0 && gc<WWID) v = qn[(size_t)(cbase+ch)*HW + gr*WWID + gc];
      pf[i] = v;
    }
  };
  issue(0);
  for (int stage=0; stage<8; stage++){
    __syncthreads();
#pragma unroll
    for (int i=0;i<15;i++) s[t + i*256] = pf[i];
    __syncthreads();
    if (stage < 7) issue(stage+1);
    int cbase = c0 + stage*4;
#pragma unroll
    for (int ch=0; ch<4; ch++){
      int c = cbase + ch;
      const float* wc = dww + c*81;
      const float* sc = s + ch*960;
      float sum0=0.f, sum1=0.f;
#pragma unroll
      for (int r=0;r<9;r++){
        float ld[10];
#pragma unroll
        for (int m2=0;m2<5;m2++){
          float2 v2 = *(const float2*)(sc + (ty+r)*40 + tx*2 + 2*m2);
          ld[2*m2]=v2.x; ld[2*m2+1]=v2.y;
        }
#pragma unroll
        for (int j=0;j<9;j++){
          float wv = wc[r*9+j];
          sum0 += wv*ld[j]; sum1 += wv*ld[j+1];
        }
      }
      float g = inv*bng[c], bet = bnb[c], db = dwb[c];
      float t0 = (sum0+db)*g + bet, t1 = (sum1+db)*g + bet;
      float p0c = pw[c], p1c = pw[C128+c];
      o0a += p0c*t0; o0b += p0c*t1;
      o1a += p1c*t0; o1b += p1c*t1;
    }
  }
  size_t base = ((size_t)n*HW + (size_t)py*WWID + px)*2;
  atomicAdd(offacc + base + 0, o0a);
  atomicAdd(offacc + base + 1, o1a);
  atomicAdd(offacc + base + 2, o0b);
  atomicAdd(offacc + base + 3, o1b);
}

// ============ finalize: offacc -> clamp -> pixel coords. grid (N*HW/256).
__global__ __launch_bounds__(256) void k_samp_fin(const float* __restrict__ offacc,
                                                  float* __restrict__ samp){
  int e = blockIdx.x*256 + threadIdx.x;
  int n = e / HW, p = e - n*HW;
  int py = p / WWID, px = p - py*WWID;
  float2 o2 = *(const float2*)(offacc + (size_t)e*2);
  const float k2 = 2.0f/351.0f;
  float ry = (0.5f+(float)py)*k2 - 1.0f, rx = (0.5f+(float)px)*k2 - 1.0f;
  float pyc = fminf(fmaxf(o2.x+ry,-0.12f),0.12f);
  float pxc = fminf(fmaxf(o2.y+rx,-0.12f),0.12f);
  float2 o; o.x = (pxc+1.f)*0.5f*351.f; o.y = (pyc+1.f)*0.5f*351.f;
  *(float2*)(samp + (size_t)e*2) = o;
  (void)n;
}

// ============ routing: logits row + top-4 indices (order-only; winsums are unscaled means).
__global__ __launch_bounds__(64) void k_routing(const float* __restrict__ qwin,
                                               const float* __restrict__ kwin,
                                               int* __restrict__ topidx){
  __shared__ float lg[128];
  const int p = blockIdx.x, n = blockIdx.y, l = threadIdx.x;
  const float* qr = qwin + ((size_t)n*121 + p)*128;
  const float* kb = kwin + (size_t)n*121*128;
  float a0 = 0.f, a1 = 0.f;
  const bool has1 = (l + 64) < 121;
  for (int c=0;c<128;c++){
    float qv = qr[c];
    a0 += qv * kb[(size_t)l*128 + c];
    if (has1) a1 += qv * kb[(size_t)(l+64)*128 + c];
  }
  lg[l] = a0;
  lg[64+l] = has1 ? a1 : -3.0e38f;
  __syncthreads();
  if (l == 0){
    for (int j=0;j<4;j++){
      float best = -3.0e38f; int bi = 0;
      for (int i=0;i<121;i++){ if (lg[i] > best){ best = lg[i]; bi = i; } }
      lg[bi] = -3.0e38f;
      topidx[((size_t)n*121 + p)*4 + j] = bi;
    }
  }
}

// ============ windowed attention. grid (121, N, 4 heads), block 256. 2 px/lane.
// kvd comes in uint-encoded (atomicMax) -> decode while staging to LDS.
__global__ __launch_bounds__(256) void k_attention(const float* __restrict__ q,
                                                   const unsigned* __restrict__ kvdk,
                                                   const int* __restrict__ topidx,
                                                   float* __restrict__ out){
  __shared__ float ks[64*32];
  __shared__ float vs[64*32];
  __shared__ int tix[4];
  const int p = blockIdx.x, n = blockIdx.y, h = blockIdx.z;
  const int t = threadIdx.x;
  if (t < 4) tix[t] = topidx[((size_t)n*121 + p)*4 + t];
  __syncthreads();
#pragma unroll
  for (int i=0;i<8;i++){
    int e = t + i*256;
    int d = e & 31, k = e >> 5;
    const unsigned* kr = kvdk + (((size_t)(n*121) + tix[k>>4])*16 + (k & 15))*256;
    ks[k*32 + d] = dec_f(kr[h*32 + d]);
    vs[k*32 + d] = dec_f(kr[128 + h*32 + d]);
  }
  __syncthreads();
  const int py0 = (p/11)*32, px0 = (p%11)*32;
  const int wv = t >> 6, l = t & 63;
  const float* qh = q + ((size_t)n*C128 + h*32)*HW;
  float* oh = out + ((size_t)n*C128 + h*32)*HW;
  for (int it=0; it<2; it++){
    int pxa = it*512 + wv*128 + l;
    int pxb = pxa + 64;
    size_t offa = (size_t)(py0 + (pxa>>5))*WWID + px0 + (pxa&31);
    size_t offb = (size_t)(py0 + (pxb>>5))*WWID + px0 + (pxb&31);
    float qa[32], qb[32], oa[32], ob[32];
#pragma unroll
    for (int d=0; d<32; d++){
      qa[d] = qh[(size_t)d*HW + offa] * SCALE_F;
      qb[d] = qh[(size_t)d*HW + offb] * SCALE_F;
      oa[d] = 0.f; ob[d] = 0.f;
    }
    float suma = 0.f, sumb = 0.f;
    for (int k=0; k<64; k++){
      const float4* kk4 = (const float4*)(ks + k*32);
      float da = 0.f, db = 0.f;
#pragma unroll
      for (int d4=0; d4<8; d4++){
        float4 kk = kk4[d4];
        da += qa[d4*4+0]*kk.x + qa[d4*4+1]*kk.y + qa[d4*4+2]*kk.z + qa[d4*4+3]*kk.w;
        db += qb[d4*4+0]*kk.x + qb[d4*4+1]*kk.y + qb[d4*4+2]*kk.z + qb[d4*4+3]*kk.w;
      }
      float pa = __expf(da), pb = __expf(db);
      suma += pa; sumb += pb;
      const float4* vv4 = (const float4*)(vs + k*32);
#pragma unroll
      for (int d4=0; d4<8; d4++){
        float4 vvv = vv4[d4];
        oa[d4*4+0] += pa*vvv.x; oa[d4*4+1] += pa*vvv.y; oa[d4*4+2] += pa*vvv.z; oa[d4*4+3] += pa*vvv.w;
        ob[d4*4+0] += pb*vvv.x; ob[d4*4+1] += pb*vvv.y; ob[d4*4+2] += pb*vvv.z; ob[d4*4+3] += pb*vvv.w;
      }
    }
    float ia = 1.0f/suma, ib2 = 1.0f/sumb;
#pragma unroll
    for (int d=0; d<32; d++){
      oh[(size_t)d*HW + offa] = oa[d]*ia;
      oh[(size_t)d*HW + offb] = ob[d]*ib2;
    }
  }
}

// ============ sec: depthwise 3x3 over V-half of kv, added into out. grid (121 tiles, C, N).
__global__ __launch_bounds__(256) void k_sec_add(const float* __restrict__ kv,
                                                 const float* __restrict__ secw,
                                                 const float* __restrict__ secb,
                                                 float* __restrict__ out){
  __shared__ float s[34*34];
  const int t = threadIdx.x;
  const int bx = blockIdx.x, c = blockIdx.y, n = blockIdx.z;
  const int X0 = (bx % 11)*32, Y0 = (bx / 11)*32;
  const float* src = kv + ((size_t)n*256 + 128 + c)*HW;
  for (int e = t; e < 1156; e += 256){
    int row = e / 34;
    int col = e - row*34;
    int gr = Y0 - 1 + row, gc = X0 - 1 + col;
    s[e] = (gr >= 0 && gr < HH && gc >= 0 && gc < WWID) ? src[gr*WWID + gc] : 0.f;
  }
  __syncthreads();
  const int tx = (t & 7)*4, ty = t >> 3;
  float w[9];
#pragma unroll
  for (int i=0;i<9;i++) w[i] = secw[c*9 + i];
  float4 r = make_float4(0.f,0.f,0.f,0.f);
#pragma unroll
  for (int kr=0; kr<3; kr++){
    const float* row = s + (ty + kr)*34 + tx;
    float a0=row[0],a1=row[1],a2=row[2],a3=row[3],a4=row[4],a5=row[5];
    float w0=w[kr*3], w1=w[kr*3+1], w2=w[kr*3+2];
    r.x += w0*a0 + w1*a1 + w2*a2;
    r.y += w0*a1 + w1*a2 + w2*a3;
    r.z += w0*a2 + w1*a3 + w2*a4;
    r.w += w0*a3 + w1*a4 + w2*a5;
  }
  float bb = secb[c];
  float* op = out + ((size_t)n*C128 + c)*HW + (size_t)(Y0+ty)*WWID + X0 + tx;
  float4 cur = *(float4*)op;
  cur.x += r.x + bb; cur.y += r.y + bb; cur.z += r.z + bb; cur.w += r.w + bb;
  *(float4*)op = cur;
}

extern "C" void kernel_launch(void* const* d_in, const int* in_sizes, int n_in,
                              void* d_out, int out_size, void* d_ws, size_t ws_size,
                              hipStream_t stream) {
  const float* x        = (const float*)d_in[0];
  const float* q_w      = (const float*)d_in[1];
  const float* q_b      = (const float*)d_in[2];
  const float* kv_w     = (const float*)d_in[3];
  const float* kv_b     = (const float*)d_in[4];
  const float* off_dw_w = (const float*)d_in[5];
  const float* off_dw_b = (const float*)d_in[6];
  const float* off_bn_g = (const float*)d_in[7];
  const float* off_bn_b = (const float*)d_in[8];
  const float* off_pw_w = (const float*)d_in[9];
  const float* sec_w    = (const float*)d_in[10];
  const float* sec_b    = (const float*)d_in[11];
  float* outp = (float*)d_out;

  float* qbuf  = (float*)d_ws;                               // N*128*HW
  float* kvbuf = qbuf  + (size_t)NIMG*C128*HW;               // N*256*HW
  float* samp  = kvbuf + (size_t)NIMG*256*HW;                // N*HW*2
  float* offacc= samp  + (size_t)NIMG*HW*2;                  // N*HW*2   (zeroed)
  float* qwin  = offacc+ (size_t)NIMG*HW*2;                  // N*121*128 (zeroed)
  float* kwin  = qwin  + (size_t)NIMG*121*128;               // N*121*128 (zeroed)
  unsigned* kvdk = (unsigned*)(kwin + (size_t)NIMG*121*128); // N*121*16*256 (zeroed)
  int*   tidx  = (int*)(kvdk + (size_t)NIMG*121*16*256);     // N*121*4
  _Float16* wfq  = (_Float16*)(tidx + NIMG*121*4);           // 16384 f16
  _Float16* wfkv = wfq + 16384;                              // 32768 f16

  // zero offacc+qwin+kwin+kvdk in one shot (contiguous)
  size_t zbytes = ((size_t)NIMG*HW*2 + (size_t)NIMG*121*128*2 + (size_t)NIMG*121*16*256) * 4;
  hipMemsetAsync(offacc, 0, zbytes, stream);

  k_wprep<<<dim3(8), 256, 0, stream>>>(q_w, wfq, 8);
  k_wprep<<<dim3(16), 256, 0, stream>>>(kv_w, wfkv, 16);
  k_conv_mfma<32, false, true, false><<<dim3(HW/64, 1, NIMG), 256, 0, stream>>>(
      x, nullptr, wfq, q_b, qbuf, qwin, nullptr);
  k_offset_part<<<dim3(11, 22, NIMG*4), 256, 0, stream>>>(
      qbuf, off_dw_w, off_dw_b, off_bn_g, off_bn_b, off_pw_w, offacc);
  k_samp_fin<<<dim3(NIMG*HW/256), 256, 0, stream>>>(offacc, samp);
  k_conv_mfma<64, true, true, true><<<dim3(HW/64, 1, NIMG), 256, 0, stream>>>(
      x, samp, wfkv, kv_b, kvbuf, kwin, kvdk);
  k_routing<<<dim3(121, NIMG), 64, 0, stream>>>(qwin, kwin, tidx);
  k_attention<<<dim3(121, NIMG, 4), 256, 0, stream>>>(qbuf, kvdk, tidx, outp);
  k_sec_add<<<dim3(121, 128, NIMG), 256, 0, stream>>>(kvbuf, sec_w, sec_b, outp);
}